// Round 1
// baseline (625.409 us; speedup 1.0000x reference)
//
#include <hip/hip_runtime.h>

// Problem constants (from reference): S=8, N=4096, F_IN=F_OUT=128
constexpr int N  = 4096;
constexpr int F  = 128;
constexpr int S  = 8;
constexpr int BM = 16;        // rows per workgroup
constexpr int BK = 64;        // k-chunk
constexpr int NC = N / BK;    // 64 chunks

typedef float f4 __attribute__((ext_vector_type(4)));

// Barrier that waits only on LDS ops (lgkmcnt), leaving global prefetch
// loads (vmcnt) in flight across the barrier.
__device__ __forceinline__ void bar_sync() {
  asm volatile("s_waitcnt lgkmcnt(0)" ::: "memory");
  __builtin_amdgcn_s_barrier();
  asm volatile("" ::: "memory");
}

__global__ __launch_bounds__(256, 1) void ggd_fused(
    const float* __restrict__ theta,
    const float* __restrict__ Ts,     // [S][N][N]
    const float* __restrict__ x,      // [N][F]
    const float* __restrict__ a,      // [N][N]
    const float* __restrict__ W,      // [F][F]  (W_fc, row-major [fo][fi])
    const float* __restrict__ bfc,    // [F]
    const float* __restrict__ alpha,  // [F]
    float* __restrict__ out)          // [N][F]
{
  __shared__ float q_lds[2][BM][BK];  // 8 KB, double buffered
  __shared__ float p_lds[BM][F];      // 8 KB, epilogue staging

  const int t  = threadIdx.x;
  const int n0 = blockIdx.x * BM;

  // theta -> registers (uniform)
  float th[S];
#pragma unroll
  for (int s = 0; s < S; ++s) th[s] = theta[s];

  // q-generation mapping: thread t covers row qr, cols [qk, qk+4)
  const int qr = t >> 4;              // 0..15
  const int qk = (t & 15) << 2;       // 0,4,...,60
  const size_t rowOff  = (size_t)(n0 + qr) * N;
  const size_t sliceSz = (size_t)N * N;

  // FMA mapping: thread t owns rows {2*ty, 2*ty+1}, feats [4*tx, 4*tx+4)
  const int tx = t & 31;              // 0..31
  const int ty = t >> 5;              // 0..7
  const int r0 = ty * 2;
  const int r1 = r0 + 1;

  f4 acc0 = (f4)(0.f);
  f4 acc1 = (f4)(0.f);

  // staging registers for the next chunk's T/a values
  f4 tv[S];
  f4 av;

  auto loadc = [&](int c) {
    const size_t off = rowOff + (size_t)c * BK + qk;
    av = *(const f4*)(a + off);
#pragma unroll
    for (int s = 0; s < S; ++s)
      tv[s] = *(const f4*)(Ts + (size_t)s * sliceSz + off);
  };

  auto qstore = [&](int buf) {
    f4 q;
#pragma unroll
    for (int j = 0; j < 4; ++j) {
      float sum = th[0] * tv[0][j];
#pragma unroll
      for (int s = 1; s < S; ++s) sum = fmaf(th[s], tv[s][j], sum);
      q[j] = av[j] * sum;
    }
    *(f4*)&q_lds[buf][qr][qk] = q;
  };

  // prologue: chunk 0
  loadc(0);
  qstore(0);

  for (int c = 0; c < NC; ++c) {
    const int buf = c & 1;
    if (c + 1 < NC) loadc(c + 1);   // issue prefetch; stays in flight past barrier

    bar_sync();                      // q_lds[buf] ready

    const float* xp = x + (size_t)c * BK * F + tx * 4;
#pragma unroll 4
    for (int kk4 = 0; kk4 < BK / 4; ++kk4) {
      f4 q0 = *(const f4*)&q_lds[buf][r0][kk4 * 4];
      f4 q1 = *(const f4*)&q_lds[buf][r1][kk4 * 4];
#pragma unroll
      for (int j = 0; j < 4; ++j) {
        f4 xv = *(const f4*)(xp + (size_t)(kk4 * 4 + j) * F);
#pragma unroll
        for (int e = 0; e < 4; ++e) {
          acc0[e] = fmaf(q0[j], xv[e], acc0[e]);
          acc1[e] = fmaf(q1[j], xv[e], acc1[e]);
        }
      }
    }

    if (c + 1 < NC) qstore(buf ^ 1); // compiler inserts vmcnt wait here
  }

  // ---- epilogue ----
  // PReLU (per input-feature channel)
  {
    f4 al = *(const f4*)(alpha + tx * 4);
#pragma unroll
    for (int j = 0; j < 4; ++j) {
      acc0[j] = acc0[j] >= 0.f ? acc0[j] : al[j] * acc0[j];
      acc1[j] = acc1[j] >= 0.f ? acc1[j] : al[j] * acc1[j];
    }
  }
  *(f4*)&p_lds[r0][tx * 4] = acc0;
  *(f4*)&p_lds[r1][tx * 4] = acc1;
  bar_sync();

  // FC: out[n][fo] = b[fo] + sum_fi p[n][fi] * W[fo][fi]
  const int rr  = t >> 4;            // 0..15
  const int fo0 = (t & 15) * 8;      // 8 consecutive outputs per thread
  float accF[8];
  {
    f4 b0 = *(const f4*)(bfc + fo0);
    f4 b1 = *(const f4*)(bfc + fo0 + 4);
#pragma unroll
    for (int j = 0; j < 4; ++j) { accF[j] = b0[j]; accF[4 + j] = b1[j]; }
  }
#pragma unroll 8
  for (int fi4 = 0; fi4 < F / 4; ++fi4) {
    f4 p4 = *(const f4*)&p_lds[rr][fi4 * 4];
#pragma unroll
    for (int j = 0; j < 8; ++j) {
      f4 w4 = *(const f4*)(W + (size_t)(fo0 + j) * F + fi4 * 4);
      accF[j] = fmaf(p4[0], w4[0],
                fmaf(p4[1], w4[1],
                fmaf(p4[2], w4[2],
                fmaf(p4[3], w4[3], accF[j]))));
    }
  }
  f4 o0, o1;
#pragma unroll
  for (int j = 0; j < 4; ++j) { o0[j] = accF[j]; o1[j] = accF[4 + j]; }
  float* op = out + (size_t)(n0 + rr) * F + fo0;
  *(f4*)op       = o0;
  *(f4*)(op + 4) = o1;
}

extern "C" void kernel_launch(void* const* d_in, const int* in_sizes, int n_in,
                              void* d_out, int out_size, void* d_ws, size_t ws_size,
                              hipStream_t stream) {
  const float* theta = (const float*)d_in[0];
  const float* Ts    = (const float*)d_in[1];
  const float* x     = (const float*)d_in[2];
  const float* a     = (const float*)d_in[3];
  const float* W     = (const float*)d_in[4];
  const float* bfc   = (const float*)d_in[5];
  const float* alpha = (const float*)d_in[6];
  float* out = (float*)d_out;

  ggd_fused<<<dim3(N / BM), dim3(256), 0, stream>>>(
      theta, Ts, x, a, W, bfc, alpha, out);
}